// Round 10
// baseline (200.444 us; speedup 1.0000x reference)
//
#include <hip/hip_runtime.h>

// ---------------------------------------------------------------------------
// TransformerEncoderCell: B=8 L=64 F=16 C=128 H=8 FF=512
// tokens NTOK = B*L*F = 8192, r = l*F+f in [0,1024), t = b*1024 + r
// proj packing: out channel o = c'*8 + h  (c' in [0,128), h in [0,8))
//
// MFMA operands in HBM as blocked 16x32 tiles (fragment-ready):
//   bf16 tile = 1KB: elem (row,k) at tile*512 + (row&15)*32 + (k&31)  [u16]
//   fp8  tile = 512B: elem (row,k) at tile*512 + (row&15)*32 + (k&31) [bytes]
//   wave fragment = tile + (lane&15)*32 + (lane>>4)*8  (contiguous)
// ws layout (bytes):
//   Qblk @0MB  : u8 [64][64][4][512]  fp8  (bh, rt, kc)    8 MB
//   Kblk @16MB : u8 [64][64][4][512]  fp8                   8 MB
//   Vblk @32MB : u8 [64][8][32][512]  fp8  (bh, c't, mt)    8 MB
//   Zblk @48MB : u16[512][32][512]    bf16 (tt, kc=o2/32)  16 MB
//     (before k_attn, reused for Xb/Wqb/Wkb/Wvb)
//   Wob @64MB, W1b, W2b (bf16 tiles)                       512 KB
//   Vcol @65MB : f32[64][128] (sum_key V per bh,c')         32 KB
//
// R26 = R25 + tail-weight conversions (wo/w1/w2) moved OFF the critical
// path: k_prep handles only x + Wq/k/v + Vcol (grid 1440); k_qkv gains two
// blockIdx.y slices (y=16: wo, y=17: w1/w2) that dispatch last and run in
// k_qkv's drain tail.  Stream order (k_attn in between) guarantees tail
// weights are ready for k_tail.  All math bitwise identical to R25.
// ---------------------------------------------------------------------------

typedef unsigned short u16;
typedef unsigned char u8;
typedef unsigned int u32;
typedef long long i64;
typedef __attribute__((ext_vector_type(2))) float f32x2;
typedef __attribute__((ext_vector_type(4))) float f32x4;
typedef __attribute__((ext_vector_type(8))) short s16x8;
typedef __attribute__((ext_vector_type(4))) unsigned short u16x4;
typedef __attribute__((ext_vector_type(2))) unsigned int u32x2;

__device__ __forceinline__ u16 f2bf(float f) {          // RNE
    union { float f; u32 u; } v; v.f = f;
    u32 u = v.u;
    u += 0x7fffu + ((u >> 16) & 1u);
    return (u16)(u >> 16);
}
__device__ __forceinline__ s16x8 ldg8(const u16* p) { return *(const s16x8*)p; }
__device__ __forceinline__ i64 ld64(const u8* p) { return *(const i64*)p; }

#define MFMA(a, b, c)  __builtin_amdgcn_mfma_f32_16x16x32_bf16((a), (b), (c), 0, 0, 0)
#define MFMA8(a, b, c) __builtin_amdgcn_mfma_f32_16x16x32_fp8_fp8((a), (b), (c), 0, 0, 0)
#define CVTPK(a, b, o, hi) ((u32)__builtin_amdgcn_cvt_pk_fp8_f32((a), (b), (o), (hi)))

// ---------------------------------------------------------------------------
// prep: fp32 -> bf16 tiled conversions (x + qkv weights) + zero Vcol.
// grid 1440 x 256.  (tail weights moved to k_qkv y-slices)
// ---------------------------------------------------------------------------
__global__ __launch_bounds__(256) void k_prep(
    const float* __restrict__ x, const float* __restrict__ wq,
    const float* __restrict__ wk, const float* __restrict__ wv,
    u16* __restrict__ Xb, u16* __restrict__ Wqb, u16* __restrict__ Wkb,
    u16* __restrict__ Wvb, float* __restrict__ Vcol)
{
    int i = blockIdx.x * 256 + threadIdx.x;
    if (i < 360448) {
        int v = i * 4;
        float4 f; u16* dst; size_t addr;
        if (v < 1048576) {
            int t = v >> 7, k = v & 127;
            f = *(const float4*)(x + v);
            dst = Xb;
            addr = (size_t)((t >> 4) * 4 + (k >> 5)) * 512 + (t & 15) * 32 + (k & 31);
        } else {
            int v2 = v - 1048576;
            int w = v2 >> 17, off = v2 & 131071;
            const float* src = (w == 0) ? wq : (w == 1) ? wk : wv;
            dst = (w == 0) ? Wqb : (w == 1) ? Wkb : Wvb;
            int o = off >> 7, k = off & 127;
            int h = o & 7, cp = o >> 3;
            f = *(const float4*)(src + off);
            addr = (size_t)((h * 8 + (cp >> 4)) * 4 + (k >> 5)) * 512 + (cp & 15) * 32 + (k & 31);
        }
        u16x4 o4; o4.x = f2bf(f.x); o4.y = f2bf(f.y); o4.z = f2bf(f.z); o4.w = f2bf(f.w);
        *(u16x4*)(dst + addr) = o4;
    } else {
        int vz = i - 360448;
        if (vz < 8192) Vcol[vz] = 0.f;
    }
}

// ---------------------------------------------------------------------------
// K1: QKV projection (bf16 MFMA), fp8 outputs.  grid (64, 18) block 256.
// y<16: GEMM slices (A from Xb, pure ldg8; Q/K swapped operands -> packed
// u32 stores).  y=16: wo->Wob conversion.  y=17: w1/w2 conversions.
// Conversion slices dispatch last -> run in the GEMM drain tail.
// ---------------------------------------------------------------------------
__global__ __launch_bounds__(256) void k_qkv(
    const u16* __restrict__ Xb,
    const u16* __restrict__ Wqb, const u16* __restrict__ Wkb, const u16* __restrict__ Wvb,
    const float* __restrict__ bq, const float* __restrict__ bk, const float* __restrict__ bv,
    const float* __restrict__ wo, const float* __restrict__ w1, const float* __restrict__ w2,
    u8* __restrict__ Qblk, u8* __restrict__ Kblk, u8* __restrict__ Vblk,
    float* __restrict__ Vcol,
    u16* __restrict__ Wob, u16* __restrict__ W1b, u16* __restrict__ W2b)
{
    const int cb = blockIdx.y;
    if (cb >= 16) {                       // tail-weight conversion slices
        const int t = blockIdx.x * 256 + threadIdx.x;
        if (cb == 16) {                   // wo: 131072 elems, 8 per thread
            #pragma unroll
            for (int s = 0; s < 8; ++s) {
                int i2 = t * 8 + s;
                int n = i2 >> 10, o2 = i2 & 1023;
                int h2 = o2 >> 7, c2 = o2 & 127;
                size_t addr = (size_t)((n >> 4) * 32 + (o2 >> 5)) * 512
                            + (n & 15) * 32 + (o2 & 31);
                Wob[addr] = f2bf(wo[n * 1024 + c2 * 8 + h2]);
            }
        } else {                          // w1/w2: 32768 vec4, 2 per thread
            #pragma unroll
            for (int s = 0; s < 2; ++s) {
                int v = (t + s * 16384) * 4;
                float4 f; u16* dst; size_t addr;
                if (v < 65536) {          // w1: 512 x 128
                    int o = v >> 7, k = v & 127;
                    f = *(const float4*)(w1 + v);
                    dst = W1b;
                    addr = (size_t)((o >> 4) * 4 + (k >> 5)) * 512 + (o & 15) * 32 + (k & 31);
                } else {                  // w2: 128 x 512
                    int v2 = v - 65536;
                    int n = v2 >> 9, k = v2 & 511;
                    f = *(const float4*)(w2 + v2);
                    dst = W2b;
                    addr = (size_t)((n >> 4) * 16 + (k >> 5)) * 512 + (n & 15) * 32 + (k & 31);
                }
                u16x4 o4; o4.x = f2bf(f.x); o4.y = f2bf(f.y); o4.z = f2bf(f.z); o4.w = f2bf(f.w);
                *(u16x4*)(dst + addr) = o4;
            }
        }
        return;
    }

    const int tid = threadIdx.x, lane = tid & 63, wid = tid >> 6;
    const int colb = lane & 15, quad = lane >> 4;
    const int fl = colb * 32 + quad * 8;
    const int t0 = blockIdx.x * 128;
    const int h = cb >> 1, c0 = (cb & 1) * 64;
    const int bi = t0 >> 10;

    const u16* at0 = Xb + (size_t)((t0 >> 4) + wid * 2) * 2048 + fl;
    const u16* at1 = at0 + 2048;
    s16x8 a0[4], a1[4];
    #pragma unroll
    for (int i = 0; i < 4; ++i) { a0[i] = ldg8(at0 + i * 512); a1[i] = ldg8(at1 + i * 512); }

    #pragma unroll
    for (int gz = 0; gz < 3; ++gz) {
        const u16* W = (gz == 0) ? Wqb : (gz == 1) ? Wkb : Wvb;
        const float* bias = (gz == 0) ? bq : (gz == 1) ? bk : bv;
        f32x4 acc[2][4] = {};
        #pragma unroll
        for (int j = 0; j < 4; ++j) {
            int cpt = (c0 >> 4) + j;
            const u16* bt = W + (size_t)((h * 8 + cpt) * 4) * 512 + fl;
            #pragma unroll
            for (int i = 0; i < 4; ++i) {
                s16x8 b = ldg8(bt + i * 512);
                if (gz < 2) {
                    // swapped: D[channel][token]
                    acc[0][j] = MFMA(b, a0[i], acc[0][j]);
                    acc[1][j] = MFMA(b, a1[i], acc[1][j]);
                } else {
                    // original: D[token][channel]
                    acc[0][j] = MFMA(a0[i], b, acc[0][j]);
                    acc[1][j] = MFMA(a1[i], b, acc[1][j]);
                }
            }
        }
        if (gz < 2) {
            u8* dst = (gz == 0) ? Qblk : Kblk;
            const int inoff = colb * 32 + quad * 4;
            #pragma unroll
            for (int j = 0; j < 4; ++j) {
                const int cbase = c0 + j * 16 + quad * 4;
                const float bs0 = bias[(cbase + 0) * 8 + h];
                const float bs1 = bias[(cbase + 1) * 8 + h];
                const float bs2 = bias[(cbase + 2) * 8 + h];
                const float bs3 = bias[(cbase + 3) * 8 + h];
                #pragma unroll
                for (int rt = 0; rt < 2; ++rt) {
                    int tb = t0 + (wid * 2 + rt) * 16;
                    int rr = tb & 1023;
                    size_t addr = (size_t)(bi * 8 + h) * 131072
                                + (size_t)((rr >> 4) * 4 + ((c0 + j * 16) >> 5)) * 512
                                + (size_t)((j & 1) * 16 + inoff);
                    u32 o = 0;
                    o = CVTPK(acc[rt][j][0] + bs0, acc[rt][j][1] + bs1, o, false);
                    o = CVTPK(acc[rt][j][2] + bs2, acc[rt][j][3] + bs3, o, true);
                    *(u32*)&dst[addr] = o;
                }
            }
        } else {
            #pragma unroll
            for (int rt = 0; rt < 2; ++rt) {
                #pragma unroll
                for (int j = 0; j < 4; ++j) {
                    int cpr = c0 + j * 16 + colb;
                    float bs = bias[cpr * 8 + h];
                    int t = t0 + (wid * 2 + rt) * 16 + quad * 4;
                    int rr = t & 1023;
                    size_t addr = (size_t)(bi * 8 + h) * 131072
                                + (size_t)((cpr >> 4) * 32 + (rr >> 5)) * 512
                                + (cpr & 15) * 32 + (rr & 31);
                    float v0 = acc[rt][j][0] + bs, v1 = acc[rt][j][1] + bs;
                    float v2 = acc[rt][j][2] + bs, v3 = acc[rt][j][3] + bs;
                    u32 o = 0;
                    o = CVTPK(v0, v1, o, false);
                    o = CVTPK(v2, v3, o, true);
                    *(u32*)&Vblk[addr] = o;
                    float s = v0 + v1 + v2 + v3;
                    s += __shfl_xor(s, 16);
                    s += __shfl_xor(s, 32);
                    if (quad == 0)
                        atomicAdd(&Vcol[(bi * 8 + h) * 128 + cpr], s);
                }
            }
        }
    }
}

// ---------------------------------------------------------------------------
// K2: attention, double softmax, all-fp8, poly exps.  grid 4096,
// block 256 (4 waves), 16 q-rows/block.  LDS 19.2 KB.
// Slab stride 1048 B.  Swapped QK^T (lane owns 4 consecutive keys).
// Phase 3: A-frag shared across 2 c'-tiles (LDS reads halved).
// ---------------------------------------------------------------------------
__global__ __launch_bounds__(256, 8) void k_attn(
    const u8* __restrict__ Qblk, const u8* __restrict__ Kblk, const u8* __restrict__ Vblk,
    const float* __restrict__ Vcol, u16* __restrict__ Zblk)
{
    __shared__ u8 sS8[16 * 1048];     // 16768 B (fp8 deviations, 16 rows)
    __shared__ float sZsum[16][17];   // 1088 B
    __shared__ float sZi[16][20];     // 1280 B (stride 20 -> 16B-aligned rows)

    const int tid = threadIdx.x, lane = tid & 63, wid = tid >> 6;   // wid 0..3
    const int colb = lane & 15, quad = lane >> 4;
    const int fl = colb * 32 + quad * 8;
    const int bid = blockIdx.x;
    const int bh = (bid & 7) + 8 * ((bid >> 3) & 7);   // XCD-L2 locality swizzle
    const int r0 = (bid >> 6) * 16;                    // 64 row-tiles of 16
    const size_t qkb = (size_t)bh * 131072;
    const float SCALE = 0.08838834764831845f;   // 1/sqrt(128)

    sZsum[tid >> 4][tid & 15] = 0.f;
    __syncthreads();

    // ---- phase 1: eps = 8*(exp(s*scale)-1) -> fp8 slab; zsum via atomics ----
    // swapped QK^T: D[key][qrow]: lane owns q-row colb, keys kt*16+quad*4+r,
    // kt = wid + 4j, j = 0..15
    const u8* qt = Qblk + qkb + (size_t)(r0 >> 4) * 2048 + fl;
    i64 aq[4];
    #pragma unroll
    for (int i = 0; i < 4; ++i) aq[i] = ld64(qt + i * 512);

    const u8* ktp = Kblk + qkb + (size_t)wid * 2048 + fl;
    u32* sp0 = (u32*)&sS8[colb * 1048 + wid * 16 + quad * 4];
    float seps[4] = {};
    #pragma unroll
    for (int j = 0; j < 16; ++j) {
        const u8* kp = ktp + (size_t)(4 * j) * 2048;
        i64 k0 = ld64(kp), k1 = ld64(kp + 512), k2 = ld64(kp + 1024), k3 = ld64(kp + 1536);
        f32x4 ac0 = {};
        ac0 = MFMA8(k0, aq[0], ac0);
        ac0 = MFMA8(k1, aq[1], ac0);
        ac0 = MFMA8(k2, aq[2], ac0);
        ac0 = MFMA8(k3, aq[3], ac0);
        // eps = 8*(e^x - 1) ~= x*(8 + x*(4 + x*4/3)), |x| <~ 0.35
        float e0[4];
        #pragma unroll
        for (int r = 0; r < 4; ++r) {
            float x0 = ac0[r] * SCALE;
            e0[r] = x0 * fmaf(x0, fmaf(x0, 1.3333334f, 4.0f), 8.0f);
            seps[r] += e0[r];
        }
        u32 o0 = 0;
        o0 = CVTPK(e0[0], e0[1], o0, false); o0 = CVTPK(e0[2], e0[3], o0, true);
        sp0[j * 16] = o0;                    // keys (wid+4j)*16 + quad*4 .. +3
    }
    // sum_j P = 8 + 0.125 * sum_j eps   (per wave's 16 key-tiles)
    #pragma unroll
    for (int r = 0; r < 4; ++r)
        atomicAdd(&sZsum[colb][quad * 4 + r], fmaf(seps[r], 0.125f, 8.0f));
    __syncthreads();

    // ---- Zi[row][g] = 1 / sum_m P ----
    sZi[tid >> 4][tid & 15] = __builtin_amdgcn_rcpf(sZsum[tid >> 4][tid & 15]);
    __syncthreads();

    // ---- phase 2: a1=P*Zi; A2 via LINEAR exp; sigma in place ----
    // w = exp(a1) ~= 1 + a1 = 1 + zi*(1 + eps/8) = fma(zi, fma(eps,.125,1), 1)
    {
        const int row = tid & 15, mb = (tid >> 4) * 4;
        f32x4 zv0 = *(const f32x4*)&sZi[row][0];
        f32x4 zv1 = *(const f32x4*)&sZi[row][4];
        f32x4 zv2 = *(const f32x4*)&sZi[row][8];
        f32x4 zv3 = *(const f32x4*)&sZi[row][12];
        float zi[16];
        zi[0] = zv0[0]; zi[1] = zv0[1]; zi[2]  = zv0[2]; zi[3]  = zv0[3];
        zi[4] = zv1[0]; zi[5] = zv1[1]; zi[6]  = zv1[2]; zi[7]  = zv1[3];
        zi[8] = zv2[0]; zi[9] = zv2[1]; zi[10] = zv2[2]; zi[11] = zv2[3];
        zi[12] = zv3[0]; zi[13] = zv3[1]; zi[14] = zv3[2]; zi[15] = zv3[3];
        #pragma unroll
        for (int tk = 0; tk < 4; ++tk) {
            int m = mb + tk;
            u8* bp = &sS8[row * 1048 + m * 16];
            u32x2 wa = *(const u32x2*)bp;
            u32x2 wb = *(const u32x2*)(bp + 8);
            u32 ww[4] = {wa.x, wa.y, wb.x, wb.y};
            float w[16]; float sum = 0.f;
            #pragma unroll
            for (int q4 = 0; q4 < 4; ++q4) {
                f32x2 eA = __builtin_amdgcn_cvt_pk_f32_fp8(ww[q4], false);
                f32x2 eB = __builtin_amdgcn_cvt_pk_f32_fp8(ww[q4], true);
                int g = q4 * 4;
                w[g+0] = fmaf(zi[g+0], fmaf(eA[0], 0.125f, 1.0f), 1.0f); sum += w[g+0];
                w[g+1] = fmaf(zi[g+1], fmaf(eA[1], 0.125f, 1.0f), 1.0f); sum += w[g+1];
                w[g+2] = fmaf(zi[g+2], fmaf(eB[0], 0.125f, 1.0f), 1.0f); sum += w[g+2];
                w[g+3] = fmaf(zi[g+3], fmaf(eB[1], 0.125f, 1.0f), 1.0f); sum += w[g+3];
            }
            float inv1024 = 1024.0f * __builtin_amdgcn_rcpf(sum);
            u32 oo[4];
            #pragma unroll
            for (int q4 = 0; q4 < 4; ++q4) {
                int g = q4 * 4;
                u32 o = 0;
                o = CVTPK(fmaf(w[g+0], inv1024, -64.f), fmaf(w[g+1], inv1024, -64.f), o, false);
                o = CVTPK(fmaf(w[g+2], inv1024, -64.f), fmaf(w[g+3], inv1024, -64.f), o, true);
                oo[q4] = o;
            }
            u32x2 oa, ob;
            oa.x = oo[0]; oa.y = oo[1]; ob.x = oo[2]; ob.y = oo[3];
            *(u32x2*)bp = oa;
            *(u32x2*)(bp + 8) = ob;
        }
    }
    __syncthreads();

    // ---- phase 3: zac = sigma @ V (fp8 MFMA).  Wave: c'tiles {wid, wid+4},
    // shared A-frag per mtile (one LDS read feeds both MFMAs). ----
    f32x4 zac[2] = {};
    const u8* aS0 = &sS8[colb * 1048 + quad * 8];
    const u8* vt0 = Vblk + qkb + (size_t)wid * 16384 + fl;
    const u8* vt1 = vt0 + 4 * 16384;
    #pragma unroll
    for (int c = 0; c < 8; ++c) {
        #pragma unroll
        for (int i = 0; i < 4; ++i) {
            int mtile = c * 4 + i;
            i64 s0 = *(const i64*)(aS0 + mtile * 32);
            i64 v0 = ld64(vt0 + mtile * 512);
            i64 v1 = ld64(vt1 + mtile * 512);
            zac[0] = MFMA8(s0, v0, zac[0]);
            zac[1] = MFMA8(s0, v1, zac[1]);
        }
    }
    const int bi = bh >> 3, hh = bh & 7;
    const int tt = (bi * 1024 + r0) >> 4;
    #pragma unroll
    for (int ct = 0; ct < 2; ++ct) {
        const int cpt = wid + 4 * ct;
        const float vsum = Vcol[bh * 128 + cpt * 16 + colb];
        size_t base = (size_t)(tt * 32 + hh * 4 + (cpt >> 1)) * 512
                    + (cpt & 1) * 16 + colb;
        #pragma unroll
        for (int r = 0; r < 4; ++r) {
            float z = fmaf(zac[ct][r], 0.0009765625f, vsum * 0.0625f);
            Zblk[base + (quad * 4 + r) * 32] = f2bf(z);
        }
    }
}

// ---------------------------------------------------------------------------
// K3: fused tail.  grid 256, block 512 (8 waves), 32 tokens/block.
// zreg (no sZ1f) + direct Zblk reads.  LDS 58.9 KB -> 2 blocks/CU.
// ---------------------------------------------------------------------------
__global__ __launch_bounds__(512, 2) void k_tail(
    const u16* __restrict__ Zblk, const u16* __restrict__ Wob, const float* __restrict__ bo,
    const float* __restrict__ x,  const float* __restrict__ g1, const float* __restrict__ be1,
    const u16* __restrict__ W1b, const float* __restrict__ b1,
    const u16* __restrict__ W2b, const float* __restrict__ b2,
    const float* __restrict__ g2, const float* __restrict__ be2,
    float* __restrict__ out)
{
    __shared__ float sC[32][132];
    __shared__ u16  sZ1h[32][136];
    __shared__ u16  sH[32][520];
    const int tid = threadIdx.x, lane = tid & 63, w = tid >> 6;
    const int colb = lane & 15, quad = lane >> 4;
    const int fl = colb * 32 + quad * 8;
    const int t0 = blockIdx.x * 32;
    float zreg[8];                    // LN1 output, reused by final LN (same thread map)

    {
        const u16* at0 = Zblk + (size_t)(blockIdx.x * 2) * 16384 + fl;
        const u16* at1 = at0 + 16384;
        const u16* bt = Wob + (size_t)w * 16384 + fl;
        f32x4 acc0 = {}, acc1 = {};
        #pragma unroll
        for (int kt = 0; kt < 32; ++kt) {
            s16x8 b = ldg8(bt + kt * 512);
            acc0 = MFMA(ldg8(at0 + kt * 512), b, acc0);
            acc1 = MFMA(ldg8(at1 + kt * 512), b, acc1);
        }
        #pragma unroll
        for (int r = 0; r < 4; ++r) {
            sC[quad * 4 + r][w * 16 + colb] = acc0[r];
            sC[16 + quad * 4 + r][w * 16 + colb] = acc1[r];
        }
    }
    __syncthreads();

    {
        const int row = tid >> 4, cg = tid & 15;
        float v[8];
        {
            f32x4 s0 = *(const f32x4*)&sC[row][cg * 8];
            f32x4 s1 = *(const f32x4*)&sC[row][cg * 8 + 4];
            float4 x0 = *(const float4*)&x[(size_t)(t0 + row) * 128 + cg * 8];
            float4 x1 = *(const float4*)&x[(size_t)(t0 + row) * 128 + cg * 8 + 4];
            float4 b0 = *(const float4*)&bo[cg * 8];
            float4 b1v = *(const float4*)&bo[cg * 8 + 4];
            v[0] = s0[0]+b0.x+x0.x; v[1] = s0[1]+b0.y+x0.y;
            v[2] = s0[2]+b0.z+x0.z; v[3] = s0[3]+b0.w+x0.w;
            v[4] = s1[0]+b1v.x+x1.x; v[5] = s1[1]+b1v.y+x1.y;
            v[6] = s1[2]+b1v.z+x1.z; v[7] = s1[3]+b1v.w+x1.w;
        }
        float s = v[0]+v[1]+v[2]+v[3]+v[4]+v[5]+v[6]+v[7];
        s += __shfl_xor(s, 1); s += __shfl_xor(s, 2);
        s += __shfl_xor(s, 4); s += __shfl_xor(s, 8);
        float mean = s * (1.0f / 128.0f);
        float d, vs = 0.f;
        #pragma unroll
        for (int j = 0; j < 8; ++j) { d = v[j] - mean; vs += d * d; }
        vs += __shfl_xor(vs, 1); vs += __shfl_xor(vs, 2);
        vs += __shfl_xor(vs, 4); vs += __shfl_xor(vs, 8);
        float rstd = rsqrtf(vs * (1.0f / 128.0f) + 1e-5f);
        float4 gg0 = *(const float4*)&g1[cg * 8], gg1 = *(const float4*)&g1[cg * 8 + 4];
        float4 bb0 = *(const float4*)&be1[cg * 8], bb1 = *(const float4*)&be1[cg * 8 + 4];
        zreg[0]=(v[0]-mean)*rstd*gg0.x+bb0.x; zreg[1]=(v[1]-mean)*rstd*gg0.y+bb0.y;
        zreg[2]=(v[2]-mean)*rstd*gg0.z+bb0.z; zreg[3]=(v[3]-mean)*rstd*gg0.w+bb0.w;
        zreg[4]=(v[4]-mean)*rstd*gg1.x+bb1.x; zreg[5]=(v[5]-mean)*rstd*gg1.y+bb1.y;
        zreg[6]=(v[6]-mean)*rstd*gg1.z+bb1.z; zreg[7]=(v[7]-mean)*rstd*gg1.w+bb1.w;
        u16x4 h0, h1;
        h0.x=f2bf(zreg[0]); h0.y=f2bf(zreg[1]); h0.z=f2bf(zreg[2]); h0.w=f2bf(zreg[3]);
        h1.x=f2bf(zreg[4]); h1.y=f2bf(zreg[5]); h1.z=f2bf(zreg[6]); h1.w=f2bf(zreg[7]);
        *(u16x4*)&sZ1h[row][cg * 8] = h0;
        *(u16x4*)&sZ1h[row][cg * 8 + 4] = h1;
    }
    __syncthreads();

    {
        s16x8 bz0[4], bz1[4];
        #pragma unroll
        for (int i = 0; i < 4; ++i) {
            bz0[i] = *(const s16x8*)&sZ1h[colb][quad * 8 + i * 32];
            bz1[i] = *(const s16x8*)&sZ1h[16 + colb][quad * 8 + i * 32];
        }
        #pragma unroll
        for (int ot = 0; ot < 4; ++ot) {
            const u16* wt = W1b + (size_t)((w * 4 + ot) * 4) * 512 + fl;
            s16x8 wf0 = ldg8(wt), wf1 = ldg8(wt + 512);
            s16x8 wf2 = ldg8(wt + 1024), wf3 = ldg8(wt + 1536);
            f32x4 a0 = {}, a1 = {};
            a0 = MFMA(wf0, bz0[0], a0); a1 = MFMA(wf0, bz1[0], a1);
            a0 = MFMA(wf1, bz0[1], a0); a1 = MFMA(wf1, bz1[1], a1);
            a0 = MFMA(wf2, bz0[2], a0); a1 = MFMA(wf2, bz1[2], a1);
            a0 = MFMA(wf3, bz0[3], a0); a1 = MFMA(wf3, bz1[3], a1);
            int o = (w * 4 + ot) * 16 + quad * 4;
            float4 bs = *(const float4*)&b1[o];
            u16x4 hv0, hv1;
            hv0.x = f2bf(fmaxf(a0[0] + bs.x, 0.f));
            hv0.y = f2bf(fmaxf(a0[1] + bs.y, 0.f));
            hv0.z = f2bf(fmaxf(a0[2] + bs.z, 0.f));
            hv0.w = f2bf(fmaxf(a0[3] + bs.w, 0.f));
            hv1.x = f2bf(fmaxf(a1[0] + bs.x, 0.f));
            hv1.y = f2bf(fmaxf(a1[1] + bs.y, 0.f));
            hv1.z = f2bf(fmaxf(a1[2] + bs.z, 0.f));
            hv1.w = f2bf(fmaxf(a1[3] + bs.w, 0.f));
            *(u16x4*)&sH[colb][o] = hv0;
            *(u16x4*)&sH[16 + colb][o] = hv1;
        }
    }
    __syncthreads();

    {
        const u16* bt = W2b + (size_t)w * 8192 + fl;
        f32x4 acc0 = {}, acc1 = {};
        #pragma unroll
        for (int kt = 0; kt < 16; ++kt) {
            s16x8 b = ldg8(bt + kt * 512);
            s16x8 a0 = *(const s16x8*)&sH[colb][quad * 8 + kt * 32];
            s16x8 a1 = *(const s16x8*)&sH[16 + colb][quad * 8 + kt * 32];
            acc0 = MFMA(a0, b, acc0);
            acc1 = MFMA(a1, b, acc1);
        }
        #pragma unroll
        for (int r = 0; r < 4; ++r) {
            sC[quad * 4 + r][w * 16 + colb] = acc0[r];
            sC[16 + quad * 4 + r][w * 16 + colb] = acc1[r];
        }
    }
    __syncthreads();

    {
        const int row = tid >> 4, cg = tid & 15;
        float v[8];
        {
            f32x4 s0 = *(const f32x4*)&sC[row][cg * 8];
            f32x4 s1 = *(const f32x4*)&sC[row][cg * 8 + 4];
            float4 b0 = *(const float4*)&b2[cg * 8];
            float4 b1v = *(const float4*)&b2[cg * 8 + 4];
            v[0] = s0[0]+b0.x+zreg[0]; v[1] = s0[1]+b0.y+zreg[1];
            v[2] = s0[2]+b0.z+zreg[2]; v[3] = s0[3]+b0.w+zreg[3];
            v[4] = s1[0]+b1v.x+zreg[4]; v[5] = s1[1]+b1v.y+zreg[5];
            v[6] = s1[2]+b1v.z+zreg[6]; v[7] = s1[3]+b1v.w+zreg[7];
        }
        float s = v[0]+v[1]+v[2]+v[3]+v[4]+v[5]+v[6]+v[7];
        s += __shfl_xor(s, 1); s += __shfl_xor(s, 2);
        s += __shfl_xor(s, 4); s += __shfl_xor(s, 8);
        float mean = s * (1.0f / 128.0f);
        float d, vs = 0.f;
        #pragma unroll
        for (int j = 0; j < 8; ++j) { d = v[j] - mean; vs += d * d; }
        vs += __shfl_xor(vs, 1); vs += __shfl_xor(vs, 2);
        vs += __shfl_xor(vs, 4); vs += __shfl_xor(vs, 8);
        float rstd = rsqrtf(vs * (1.0f / 128.0f) + 1e-5f);
        float4 gg0 = *(const float4*)&g2[cg * 8], gg1 = *(const float4*)&g2[cg * 8 + 4];
        float4 bb0 = *(const float4*)&be2[cg * 8], bb1 = *(const float4*)&be2[cg * 8 + 4];
        size_t ob = (size_t)(t0 + row) * 128 + cg * 8;
        *(float4*)&out[ob] = make_float4(
            (v[0]-mean)*rstd*gg0.x+bb0.x, (v[1]-mean)*rstd*gg0.y+bb0.y,
            (v[2]-mean)*rstd*gg0.z+bb0.z, (v[3]-mean)*rstd*gg0.w+bb0.w);
        *(float4*)&out[ob + 4] = make_float4(
            (v[4]-mean)*rstd*gg1.x+bb1.x, (v[5]-mean)*rstd*gg1.y+bb1.y,
            (v[6]-mean)*rstd*gg1.z+bb1.z, (v[7]-mean)*rstd*gg1.w+bb1.w);
    }
}

// ---------------------------------------------------------------------------
extern "C" void kernel_launch(void* const* d_in, const int* in_sizes, int n_in,
                              void* d_out, int out_size, void* d_ws, size_t ws_size,
                              hipStream_t stream)
{
    (void)in_sizes; (void)n_in; (void)out_size; (void)ws_size;
    const float* x   = (const float*)d_in[0];
    const float* wq  = (const float*)d_in[1];
    const float* bq  = (const float*)d_in[2];
    const float* wk  = (const float*)d_in[3];
    const float* bk  = (const float*)d_in[4];
    const float* wv  = (const float*)d_in[5];
    const float* bv  = (const float*)d_in[6];
    const float* wo  = (const float*)d_in[7];
    const float* bo  = (const float*)d_in[8];
    const float* g1  = (const float*)d_in[9];
    const float* be1 = (const float*)d_in[10];
    const float* w1  = (const float*)d_in[11];
    const float* b1  = (const float*)d_in[12];
    const float* w2  = (const float*)d_in[13];
    const float* b2  = (const float*)d_in[14];
    const float* g2  = (const float*)d_in[15];
    const float* be2 = (const float*)d_in[16];

    char* ws = (char*)d_ws;
    const size_t MB = (size_t)1 << 20;
    u8*    Qblk = (u8*)(ws + 0 * MB);
    u8*    Kblk = (u8*)(ws + 16 * MB);
    u8*    Vblk = (u8*)(ws + 32 * MB);
    u16*   Zblk = (u16*)(ws + 48 * MB);
    // pre-attention scratch in Zblk region (dead after k_qkv):
    u16*   Xb  = (u16*)(ws + 48 * MB);
    u16*   Wqb = (u16*)(ws + 50 * MB);
    u16*   Wkb = (u16*)(ws + 50 * MB + 262144);
    u16*   Wvb = (u16*)(ws + 50 * MB + 524288);
    // tail weights + Vcol (own region, no aliasing):
    u16*   Wob  = (u16*)(ws + 64 * MB);
    u16*   W1b  = (u16*)(ws + 64 * MB + 524288);
    u16*   W2b  = (u16*)(ws + 64 * MB + 786432);
    float* Vcol = (float*)(ws + 65 * MB);
    float* out = (float*)d_out;

    k_prep<<<1440, 256, 0, stream>>>(x, wq, wk, wv, Xb, Wqb, Wkb, Wvb, Vcol);
    k_qkv<<<dim3(64, 18), 256, 0, stream>>>(Xb, Wqb, Wkb, Wvb, bq, bk, bv,
                                            wo, w1, w2,
                                            Qblk, Kblk, Vblk, Vcol,
                                            Wob, W1b, W2b);
    k_attn<<<4096, 256, 0, stream>>>(Qblk, Kblk, Vblk, Vcol, Zblk);
    k_tail<<<256, 512, 0, stream>>>(Zblk, Wob, bo, x, g1, be1, W1b, b1, W2b, b2, g2, be2, out);
}

// Round 11
// 198.823 us; speedup vs baseline: 1.0082x; 1.0082x over previous
//
#include <hip/hip_runtime.h>

// ---------------------------------------------------------------------------
// TransformerEncoderCell: B=8 L=64 F=16 C=128 H=8 FF=512
// tokens NTOK = B*L*F = 8192, r = l*F+f in [0,1024), t = b*1024 + r
// proj packing: out channel o = c'*8 + h  (c' in [0,128), h in [0,8))
//
// MFMA operands in HBM as blocked 16x32 tiles (fragment-ready):
//   bf16 tile = 1KB: elem (row,k) at tile*512 + (row&15)*32 + (k&31)  [u16]
//   fp8  tile = 512B: elem (row,k) at tile*512 + (row&15)*32 + (k&31) [bytes]
//   wave fragment = tile + (lane&15)*32 + (lane>>4)*8  (contiguous)
// ws layout (bytes):
//   Qblk @0MB  : u8 [64][64][4][512]  fp8  (bh, rt, kc)    8 MB
//   Kblk @16MB : u8 [64][64][4][512]  fp8                   8 MB
//   Vblk @32MB : u8 [64][8][32][512]  fp8  (bh, c't, mt)    8 MB
//   Zblk @48MB : u16[512][32][512]    bf16 (tt, kc=o2/32)  16 MB
//     (before k_attn, reused for Xb/Wqb/Wkb/Wvb)
//   Wob @64MB, W1b, W2b (bf16 tiles)                       512 KB
//   Vcol @65MB : f32[64][128] (sum_key V per bh,c')         32 KB
//
// R27 = R26 + k_tail wave-doubling: block 512 -> 1024 (8 -> 16 waves/CU;
// grid 256 pins 1 block/CU so occupancy was 25%).  MFMA phases split their
// kt-range across wave pairs (per-block global traffic UNCHANGED, per-wave
// chains halved); partials in sC[2][..] summed inside the LN reads.  LDS
// 75.8 KB.  LN phases guard tid<512.  Other kernels identical to R26.
// ---------------------------------------------------------------------------

typedef unsigned short u16;
typedef unsigned char u8;
typedef unsigned int u32;
typedef long long i64;
typedef __attribute__((ext_vector_type(2))) float f32x2;
typedef __attribute__((ext_vector_type(4))) float f32x4;
typedef __attribute__((ext_vector_type(8))) short s16x8;
typedef __attribute__((ext_vector_type(4))) unsigned short u16x4;
typedef __attribute__((ext_vector_type(2))) unsigned int u32x2;

__device__ __forceinline__ u16 f2bf(float f) {          // RNE
    union { float f; u32 u; } v; v.f = f;
    u32 u = v.u;
    u += 0x7fffu + ((u >> 16) & 1u);
    return (u16)(u >> 16);
}
__device__ __forceinline__ s16x8 ldg8(const u16* p) { return *(const s16x8*)p; }
__device__ __forceinline__ i64 ld64(const u8* p) { return *(const i64*)p; }

#define MFMA(a, b, c)  __builtin_amdgcn_mfma_f32_16x16x32_bf16((a), (b), (c), 0, 0, 0)
#define MFMA8(a, b, c) __builtin_amdgcn_mfma_f32_16x16x32_fp8_fp8((a), (b), (c), 0, 0, 0)
#define CVTPK(a, b, o, hi) ((u32)__builtin_amdgcn_cvt_pk_fp8_f32((a), (b), (o), (hi)))

// ---------------------------------------------------------------------------
// prep: fp32 -> bf16 tiled conversions (x + qkv weights) + zero Vcol.
// grid 1440 x 256.
// ---------------------------------------------------------------------------
__global__ __launch_bounds__(256) void k_prep(
    const float* __restrict__ x, const float* __restrict__ wq,
    const float* __restrict__ wk, const float* __restrict__ wv,
    u16* __restrict__ Xb, u16* __restrict__ Wqb, u16* __restrict__ Wkb,
    u16* __restrict__ Wvb, float* __restrict__ Vcol)
{
    int i = blockIdx.x * 256 + threadIdx.x;
    if (i < 360448) {
        int v = i * 4;
        float4 f; u16* dst; size_t addr;
        if (v < 1048576) {
            int t = v >> 7, k = v & 127;
            f = *(const float4*)(x + v);
            dst = Xb;
            addr = (size_t)((t >> 4) * 4 + (k >> 5)) * 512 + (t & 15) * 32 + (k & 31);
        } else {
            int v2 = v - 1048576;
            int w = v2 >> 17, off = v2 & 131071;
            const float* src = (w == 0) ? wq : (w == 1) ? wk : wv;
            dst = (w == 0) ? Wqb : (w == 1) ? Wkb : Wvb;
            int o = off >> 7, k = off & 127;
            int h = o & 7, cp = o >> 3;
            f = *(const float4*)(src + off);
            addr = (size_t)((h * 8 + (cp >> 4)) * 4 + (k >> 5)) * 512 + (cp & 15) * 32 + (k & 31);
        }
        u16x4 o4; o4.x = f2bf(f.x); o4.y = f2bf(f.y); o4.z = f2bf(f.z); o4.w = f2bf(f.w);
        *(u16x4*)(dst + addr) = o4;
    } else {
        int vz = i - 360448;
        if (vz < 8192) Vcol[vz] = 0.f;
    }
}

// ---------------------------------------------------------------------------
// K1: QKV projection (bf16 MFMA), fp8 outputs.  grid (64, 18) block 256.
// y<16: GEMM slices.  y=16: wo->Wob.  y=17: w1/w2 conversions.
// ---------------------------------------------------------------------------
__global__ __launch_bounds__(256) void k_qkv(
    const u16* __restrict__ Xb,
    const u16* __restrict__ Wqb, const u16* __restrict__ Wkb, const u16* __restrict__ Wvb,
    const float* __restrict__ bq, const float* __restrict__ bk, const float* __restrict__ bv,
    const float* __restrict__ wo, const float* __restrict__ w1, const float* __restrict__ w2,
    u8* __restrict__ Qblk, u8* __restrict__ Kblk, u8* __restrict__ Vblk,
    float* __restrict__ Vcol,
    u16* __restrict__ Wob, u16* __restrict__ W1b, u16* __restrict__ W2b)
{
    const int cb = blockIdx.y;
    if (cb >= 16) {                       // tail-weight conversion slices
        const int t = blockIdx.x * 256 + threadIdx.x;
        if (cb == 16) {                   // wo: 131072 elems, 8 per thread
            #pragma unroll
            for (int s = 0; s < 8; ++s) {
                int i2 = t * 8 + s;
                int n = i2 >> 10, o2 = i2 & 1023;
                int h2 = o2 >> 7, c2 = o2 & 127;
                size_t addr = (size_t)((n >> 4) * 32 + (o2 >> 5)) * 512
                            + (n & 15) * 32 + (o2 & 31);
                Wob[addr] = f2bf(wo[n * 1024 + c2 * 8 + h2]);
            }
        } else {                          // w1/w2: 32768 vec4, 2 per thread
            #pragma unroll
            for (int s = 0; s < 2; ++s) {
                int v = (t + s * 16384) * 4;
                float4 f; u16* dst; size_t addr;
                if (v < 65536) {          // w1: 512 x 128
                    int o = v >> 7, k = v & 127;
                    f = *(const float4*)(w1 + v);
                    dst = W1b;
                    addr = (size_t)((o >> 4) * 4 + (k >> 5)) * 512 + (o & 15) * 32 + (k & 31);
                } else {                  // w2: 128 x 512
                    int v2 = v - 65536;
                    int n = v2 >> 9, k = v2 & 511;
                    f = *(const float4*)(w2 + v2);
                    dst = W2b;
                    addr = (size_t)((n >> 4) * 16 + (k >> 5)) * 512 + (n & 15) * 32 + (k & 31);
                }
                u16x4 o4; o4.x = f2bf(f.x); o4.y = f2bf(f.y); o4.z = f2bf(f.z); o4.w = f2bf(f.w);
                *(u16x4*)(dst + addr) = o4;
            }
        }
        return;
    }

    const int tid = threadIdx.x, lane = tid & 63, wid = tid >> 6;
    const int colb = lane & 15, quad = lane >> 4;
    const int fl = colb * 32 + quad * 8;
    const int t0 = blockIdx.x * 128;
    const int h = cb >> 1, c0 = (cb & 1) * 64;
    const int bi = t0 >> 10;

    const u16* at0 = Xb + (size_t)((t0 >> 4) + wid * 2) * 2048 + fl;
    const u16* at1 = at0 + 2048;
    s16x8 a0[4], a1[4];
    #pragma unroll
    for (int i = 0; i < 4; ++i) { a0[i] = ldg8(at0 + i * 512); a1[i] = ldg8(at1 + i * 512); }

    #pragma unroll
    for (int gz = 0; gz < 3; ++gz) {
        const u16* W = (gz == 0) ? Wqb : (gz == 1) ? Wkb : Wvb;
        const float* bias = (gz == 0) ? bq : (gz == 1) ? bk : bv;
        f32x4 acc[2][4] = {};
        #pragma unroll
        for (int j = 0; j < 4; ++j) {
            int cpt = (c0 >> 4) + j;
            const u16* bt = W + (size_t)((h * 8 + cpt) * 4) * 512 + fl;
            #pragma unroll
            for (int i = 0; i < 4; ++i) {
                s16x8 b = ldg8(bt + i * 512);
                if (gz < 2) {
                    acc[0][j] = MFMA(b, a0[i], acc[0][j]);
                    acc[1][j] = MFMA(b, a1[i], acc[1][j]);
                } else {
                    acc[0][j] = MFMA(a0[i], b, acc[0][j]);
                    acc[1][j] = MFMA(a1[i], b, acc[1][j]);
                }
            }
        }
        if (gz < 2) {
            u8* dst = (gz == 0) ? Qblk : Kblk;
            const int inoff = colb * 32 + quad * 4;
            #pragma unroll
            for (int j = 0; j < 4; ++j) {
                const int cbase = c0 + j * 16 + quad * 4;
                const float bs0 = bias[(cbase + 0) * 8 + h];
                const float bs1 = bias[(cbase + 1) * 8 + h];
                const float bs2 = bias[(cbase + 2) * 8 + h];
                const float bs3 = bias[(cbase + 3) * 8 + h];
                #pragma unroll
                for (int rt = 0; rt < 2; ++rt) {
                    int tb = t0 + (wid * 2 + rt) * 16;
                    int rr = tb & 1023;
                    size_t addr = (size_t)(bi * 8 + h) * 131072
                                + (size_t)((rr >> 4) * 4 + ((c0 + j * 16) >> 5)) * 512
                                + (size_t)((j & 1) * 16 + inoff);
                    u32 o = 0;
                    o = CVTPK(acc[rt][j][0] + bs0, acc[rt][j][1] + bs1, o, false);
                    o = CVTPK(acc[rt][j][2] + bs2, acc[rt][j][3] + bs3, o, true);
                    *(u32*)&dst[addr] = o;
                }
            }
        } else {
            #pragma unroll
            for (int rt = 0; rt < 2; ++rt) {
                #pragma unroll
                for (int j = 0; j < 4; ++j) {
                    int cpr = c0 + j * 16 + colb;
                    float bs = bias[cpr * 8 + h];
                    int t = t0 + (wid * 2 + rt) * 16 + quad * 4;
                    int rr = t & 1023;
                    size_t addr = (size_t)(bi * 8 + h) * 131072
                                + (size_t)((cpr >> 4) * 32 + (rr >> 5)) * 512
                                + (cpr & 15) * 32 + (rr & 31);
                    float v0 = acc[rt][j][0] + bs, v1 = acc[rt][j][1] + bs;
                    float v2 = acc[rt][j][2] + bs, v3 = acc[rt][j][3] + bs;
                    u32 o = 0;
                    o = CVTPK(v0, v1, o, false);
                    o = CVTPK(v2, v3, o, true);
                    *(u32*)&Vblk[addr] = o;
                    float s = v0 + v1 + v2 + v3;
                    s += __shfl_xor(s, 16);
                    s += __shfl_xor(s, 32);
                    if (quad == 0)
                        atomicAdd(&Vcol[(bi * 8 + h) * 128 + cpr], s);
                }
            }
        }
    }
}

// ---------------------------------------------------------------------------
// K2: attention, double softmax, all-fp8, poly exps.  grid 4096,
// block 256 (4 waves), 16 q-rows/block.  LDS 19.2 KB.
// ---------------------------------------------------------------------------
__global__ __launch_bounds__(256, 8) void k_attn(
    const u8* __restrict__ Qblk, const u8* __restrict__ Kblk, const u8* __restrict__ Vblk,
    const float* __restrict__ Vcol, u16* __restrict__ Zblk)
{
    __shared__ u8 sS8[16 * 1048];     // 16768 B (fp8 deviations, 16 rows)
    __shared__ float sZsum[16][17];   // 1088 B
    __shared__ float sZi[16][20];     // 1280 B (stride 20 -> 16B-aligned rows)

    const int tid = threadIdx.x, lane = tid & 63, wid = tid >> 6;   // wid 0..3
    const int colb = lane & 15, quad = lane >> 4;
    const int fl = colb * 32 + quad * 8;
    const int bid = blockIdx.x;
    const int bh = (bid & 7) + 8 * ((bid >> 3) & 7);   // XCD-L2 locality swizzle
    const int r0 = (bid >> 6) * 16;                    // 64 row-tiles of 16
    const size_t qkb = (size_t)bh * 131072;
    const float SCALE = 0.08838834764831845f;   // 1/sqrt(128)

    sZsum[tid >> 4][tid & 15] = 0.f;
    __syncthreads();

    // ---- phase 1: eps = 8*(exp(s*scale)-1) -> fp8 slab; zsum via atomics ----
    const u8* qt = Qblk + qkb + (size_t)(r0 >> 4) * 2048 + fl;
    i64 aq[4];
    #pragma unroll
    for (int i = 0; i < 4; ++i) aq[i] = ld64(qt + i * 512);

    const u8* ktp = Kblk + qkb + (size_t)wid * 2048 + fl;
    u32* sp0 = (u32*)&sS8[colb * 1048 + wid * 16 + quad * 4];
    float seps[4] = {};
    #pragma unroll
    for (int j = 0; j < 16; ++j) {
        const u8* kp = ktp + (size_t)(4 * j) * 2048;
        i64 k0 = ld64(kp), k1 = ld64(kp + 512), k2 = ld64(kp + 1024), k3 = ld64(kp + 1536);
        f32x4 ac0 = {};
        ac0 = MFMA8(k0, aq[0], ac0);
        ac0 = MFMA8(k1, aq[1], ac0);
        ac0 = MFMA8(k2, aq[2], ac0);
        ac0 = MFMA8(k3, aq[3], ac0);
        float e0[4];
        #pragma unroll
        for (int r = 0; r < 4; ++r) {
            float x0 = ac0[r] * SCALE;
            e0[r] = x0 * fmaf(x0, fmaf(x0, 1.3333334f, 4.0f), 8.0f);
            seps[r] += e0[r];
        }
        u32 o0 = 0;
        o0 = CVTPK(e0[0], e0[1], o0, false); o0 = CVTPK(e0[2], e0[3], o0, true);
        sp0[j * 16] = o0;                    // keys (wid+4j)*16 + quad*4 .. +3
    }
    #pragma unroll
    for (int r = 0; r < 4; ++r)
        atomicAdd(&sZsum[colb][quad * 4 + r], fmaf(seps[r], 0.125f, 8.0f));
    __syncthreads();

    // ---- Zi[row][g] = 1 / sum_m P ----
    sZi[tid >> 4][tid & 15] = __builtin_amdgcn_rcpf(sZsum[tid >> 4][tid & 15]);
    __syncthreads();

    // ---- phase 2: a1=P*Zi; A2 via LINEAR exp; sigma in place ----
    {
        const int row = tid & 15, mb = (tid >> 4) * 4;
        f32x4 zv0 = *(const f32x4*)&sZi[row][0];
        f32x4 zv1 = *(const f32x4*)&sZi[row][4];
        f32x4 zv2 = *(const f32x4*)&sZi[row][8];
        f32x4 zv3 = *(const f32x4*)&sZi[row][12];
        float zi[16];
        zi[0] = zv0[0]; zi[1] = zv0[1]; zi[2]  = zv0[2]; zi[3]  = zv0[3];
        zi[4] = zv1[0]; zi[5] = zv1[1]; zi[6]  = zv1[2]; zi[7]  = zv1[3];
        zi[8] = zv2[0]; zi[9] = zv2[1]; zi[10] = zv2[2]; zi[11] = zv2[3];
        zi[12] = zv3[0]; zi[13] = zv3[1]; zi[14] = zv3[2]; zi[15] = zv3[3];
        #pragma unroll
        for (int tk = 0; tk < 4; ++tk) {
            int m = mb + tk;
            u8* bp = &sS8[row * 1048 + m * 16];
            u32x2 wa = *(const u32x2*)bp;
            u32x2 wb = *(const u32x2*)(bp + 8);
            u32 ww[4] = {wa.x, wa.y, wb.x, wb.y};
            float w[16]; float sum = 0.f;
            #pragma unroll
            for (int q4 = 0; q4 < 4; ++q4) {
                f32x2 eA = __builtin_amdgcn_cvt_pk_f32_fp8(ww[q4], false);
                f32x2 eB = __builtin_amdgcn_cvt_pk_f32_fp8(ww[q4], true);
                int g = q4 * 4;
                w[g+0] = fmaf(zi[g+0], fmaf(eA[0], 0.125f, 1.0f), 1.0f); sum += w[g+0];
                w[g+1] = fmaf(zi[g+1], fmaf(eA[1], 0.125f, 1.0f), 1.0f); sum += w[g+1];
                w[g+2] = fmaf(zi[g+2], fmaf(eB[0], 0.125f, 1.0f), 1.0f); sum += w[g+2];
                w[g+3] = fmaf(zi[g+3], fmaf(eB[1], 0.125f, 1.0f), 1.0f); sum += w[g+3];
            }
            float inv1024 = 1024.0f * __builtin_amdgcn_rcpf(sum);
            u32 oo[4];
            #pragma unroll
            for (int q4 = 0; q4 < 4; ++q4) {
                int g = q4 * 4;
                u32 o = 0;
                o = CVTPK(fmaf(w[g+0], inv1024, -64.f), fmaf(w[g+1], inv1024, -64.f), o, false);
                o = CVTPK(fmaf(w[g+2], inv1024, -64.f), fmaf(w[g+3], inv1024, -64.f), o, true);
                oo[q4] = o;
            }
            u32x2 oa, ob;
            oa.x = oo[0]; oa.y = oo[1]; ob.x = oo[2]; ob.y = oo[3];
            *(u32x2*)bp = oa;
            *(u32x2*)(bp + 8) = ob;
        }
    }
    __syncthreads();

    // ---- phase 3: zac = sigma @ V (fp8 MFMA), shared A-frag, 2 c'-tiles ----
    f32x4 zac[2] = {};
    const u8* aS0 = &sS8[colb * 1048 + quad * 8];
    const u8* vt0 = Vblk + qkb + (size_t)wid * 16384 + fl;
    const u8* vt1 = vt0 + 4 * 16384;
    #pragma unroll
    for (int c = 0; c < 8; ++c) {
        #pragma unroll
        for (int i = 0; i < 4; ++i) {
            int mtile = c * 4 + i;
            i64 s0 = *(const i64*)(aS0 + mtile * 32);
            i64 v0 = ld64(vt0 + mtile * 512);
            i64 v1 = ld64(vt1 + mtile * 512);
            zac[0] = MFMA8(s0, v0, zac[0]);
            zac[1] = MFMA8(s0, v1, zac[1]);
        }
    }
    const int bi = bh >> 3, hh = bh & 7;
    const int tt = (bi * 1024 + r0) >> 4;
    #pragma unroll
    for (int ct = 0; ct < 2; ++ct) {
        const int cpt = wid + 4 * ct;
        const float vsum = Vcol[bh * 128 + cpt * 16 + colb];
        size_t base = (size_t)(tt * 32 + hh * 4 + (cpt >> 1)) * 512
                    + (cpt & 1) * 16 + colb;
        #pragma unroll
        for (int r = 0; r < 4; ++r) {
            float z = fmaf(zac[ct][r], 0.0009765625f, vsum * 0.0625f);
            Zblk[base + (quad * 4 + r) * 32] = f2bf(z);
        }
    }
}

// ---------------------------------------------------------------------------
// K3: fused tail.  R27: grid 256, block 1024 (16 waves), 32 tokens/block.
// MFMA phases split kt across wave pairs (kh = w>>3); partials in sC[2]
// summed in the LN reads.  Per-block global traffic unchanged.
// LDS: sC 33.8 + sZ1h 8.7 + sH 33.3 = 75.8 KB (1 block/CU; grid pins that).
// ---------------------------------------------------------------------------
__global__ __launch_bounds__(1024, 1) void k_tail(
    const u16* __restrict__ Zblk, const u16* __restrict__ Wob, const float* __restrict__ bo,
    const float* __restrict__ x,  const float* __restrict__ g1, const float* __restrict__ be1,
    const u16* __restrict__ W1b, const float* __restrict__ b1,
    const u16* __restrict__ W2b, const float* __restrict__ b2,
    const float* __restrict__ g2, const float* __restrict__ be2,
    float* __restrict__ out)
{
    __shared__ float sC[2][32][132];
    __shared__ u16  sZ1h[32][136];
    __shared__ u16  sH[32][520];
    const int tid = threadIdx.x, lane = tid & 63, w = tid >> 6;   // w 0..15
    const int ct = w & 7, kh = w >> 3;
    const int colb = lane & 15, quad = lane >> 4;
    const int fl = colb * 32 + quad * 8;
    const int t0 = blockIdx.x * 32;
    float zreg[8];                    // LN1 output, reused by final LN (tid<512 map)

    // ---- phase A: C = Z @ Wo^T, kt-halves across wave pairs ----
    {
        const u16* at0 = Zblk + (size_t)(blockIdx.x * 2) * 16384 + fl;
        const u16* at1 = at0 + 16384;
        const u16* bt = Wob + (size_t)ct * 16384 + fl;
        f32x4 acc0 = {}, acc1 = {};
        #pragma unroll
        for (int k = 0; k < 16; ++k) {
            int kt = kh * 16 + k;
            s16x8 b = ldg8(bt + kt * 512);
            acc0 = MFMA(ldg8(at0 + kt * 512), b, acc0);
            acc1 = MFMA(ldg8(at1 + kt * 512), b, acc1);
        }
        #pragma unroll
        for (int r = 0; r < 4; ++r) {
            sC[kh][quad * 4 + r][ct * 16 + colb] = acc0[r];
            sC[kh][16 + quad * 4 + r][ct * 16 + colb] = acc1[r];
        }
    }
    __syncthreads();

    // ---- LN1 (tid < 512): sum partials, +bo +x, layernorm -> zreg, sZ1h ----
    if (tid < 512) {
        const int row = tid >> 4, cg = tid & 15;
        float v[8];
        {
            f32x4 sA0 = *(const f32x4*)&sC[0][row][cg * 8];
            f32x4 sA1 = *(const f32x4*)&sC[0][row][cg * 8 + 4];
            f32x4 sB0 = *(const f32x4*)&sC[1][row][cg * 8];
            f32x4 sB1 = *(const f32x4*)&sC[1][row][cg * 8 + 4];
            float4 x0 = *(const float4*)&x[(size_t)(t0 + row) * 128 + cg * 8];
            float4 x1 = *(const float4*)&x[(size_t)(t0 + row) * 128 + cg * 8 + 4];
            float4 b0 = *(const float4*)&bo[cg * 8];
            float4 b1v = *(const float4*)&bo[cg * 8 + 4];
            v[0] = (sA0[0]+sB0[0])+b0.x+x0.x; v[1] = (sA0[1]+sB0[1])+b0.y+x0.y;
            v[2] = (sA0[2]+sB0[2])+b0.z+x0.z; v[3] = (sA0[3]+sB0[3])+b0.w+x0.w;
            v[4] = (sA1[0]+sB1[0])+b1v.x+x1.x; v[5] = (sA1[1]+sB1[1])+b1v.y+x1.y;
            v[6] = (sA1[2]+sB1[2])+b1v.z+x1.z; v[7] = (sA1[3]+sB1[3])+b1v.w+x1.w;
        }
        float s = v[0]+v[1]+v[2]+v[3]+v[4]+v[5]+v[6]+v[7];
        s += __shfl_xor(s, 1); s += __shfl_xor(s, 2);
        s += __shfl_xor(s, 4); s += __shfl_xor(s, 8);
        float mean = s * (1.0f / 128.0f);
        float d, vs = 0.f;
        #pragma unroll
        for (int j = 0; j < 8; ++j) { d = v[j] - mean; vs += d * d; }
        vs += __shfl_xor(vs, 1); vs += __shfl_xor(vs, 2);
        vs += __shfl_xor(vs, 4); vs += __shfl_xor(vs, 8);
        float rstd = rsqrtf(vs * (1.0f / 128.0f) + 1e-5f);
        float4 gg0 = *(const float4*)&g1[cg * 8], gg1 = *(const float4*)&g1[cg * 8 + 4];
        float4 bb0 = *(const float4*)&be1[cg * 8], bb1 = *(const float4*)&be1[cg * 8 + 4];
        zreg[0]=(v[0]-mean)*rstd*gg0.x+bb0.x; zreg[1]=(v[1]-mean)*rstd*gg0.y+bb0.y;
        zreg[2]=(v[2]-mean)*rstd*gg0.z+bb0.z; zreg[3]=(v[3]-mean)*rstd*gg0.w+bb0.w;
        zreg[4]=(v[4]-mean)*rstd*gg1.x+bb1.x; zreg[5]=(v[5]-mean)*rstd*gg1.y+bb1.y;
        zreg[6]=(v[6]-mean)*rstd*gg1.z+bb1.z; zreg[7]=(v[7]-mean)*rstd*gg1.w+bb1.w;
        u16x4 h0, h1;
        h0.x=f2bf(zreg[0]); h0.y=f2bf(zreg[1]); h0.z=f2bf(zreg[2]); h0.w=f2bf(zreg[3]);
        h1.x=f2bf(zreg[4]); h1.y=f2bf(zreg[5]); h1.z=f2bf(zreg[6]); h1.w=f2bf(zreg[7]);
        *(u16x4*)&sZ1h[row][cg * 8] = h0;
        *(u16x4*)&sZ1h[row][cg * 8 + 4] = h1;
    }
    __syncthreads();

    // ---- FFN1: H = relu(Z1 @ W1^T + b1), 2 output tiles per wave ----
    {
        s16x8 bz0[4], bz1[4];
        #pragma unroll
        for (int i = 0; i < 4; ++i) {
            bz0[i] = *(const s16x8*)&sZ1h[colb][quad * 8 + i * 32];
            bz1[i] = *(const s16x8*)&sZ1h[16 + colb][quad * 8 + i * 32];
        }
        #pragma unroll
        for (int p = 0; p < 2; ++p) {
            const int otg = w * 2 + p;                 // 0..31
            const u16* wt = W1b + (size_t)(otg * 4) * 512 + fl;
            s16x8 wf0 = ldg8(wt), wf1 = ldg8(wt + 512);
            s16x8 wf2 = ldg8(wt + 1024), wf3 = ldg8(wt + 1536);
            f32x4 a0 = {}, a1 = {};
            a0 = MFMA(wf0, bz0[0], a0); a1 = MFMA(wf0, bz1[0], a1);
            a0 = MFMA(wf1, bz0[1], a0); a1 = MFMA(wf1, bz1[1], a1);
            a0 = MFMA(wf2, bz0[2], a0); a1 = MFMA(wf2, bz1[2], a1);
            a0 = MFMA(wf3, bz0[3], a0); a1 = MFMA(wf3, bz1[3], a1);
            int o = otg * 16 + quad * 4;
            float4 bs = *(const float4*)&b1[o];
            u16x4 hv0, hv1;
            hv0.x = f2bf(fmaxf(a0[0] + bs.x, 0.f));
            hv0.y = f2bf(fmaxf(a0[1] + bs.y, 0.f));
            hv0.z = f2bf(fmaxf(a0[2] + bs.z, 0.f));
            hv0.w = f2bf(fmaxf(a0[3] + bs.w, 0.f));
            hv1.x = f2bf(fmaxf(a1[0] + bs.x, 0.f));
            hv1.y = f2bf(fmaxf(a1[1] + bs.y, 0.f));
            hv1.z = f2bf(fmaxf(a1[2] + bs.z, 0.f));
            hv1.w = f2bf(fmaxf(a1[3] + bs.w, 0.f));
            *(u16x4*)&sH[colb][o] = hv0;
            *(u16x4*)&sH[16 + colb][o] = hv1;
        }
    }
    __syncthreads();

    // ---- FFN2: C2 = H @ W2^T, kt-halves across wave pairs ----
    {
        const u16* bt = W2b + (size_t)ct * 8192 + fl;
        f32x4 acc0 = {}, acc1 = {};
        #pragma unroll
        for (int k = 0; k < 8; ++k) {
            int kt = kh * 8 + k;
            s16x8 b = ldg8(bt + kt * 512);
            s16x8 a0 = *(const s16x8*)&sH[colb][quad * 8 + kt * 32];
            s16x8 a1 = *(const s16x8*)&sH[16 + colb][quad * 8 + kt * 32];
            acc0 = MFMA(a0, b, acc0);
            acc1 = MFMA(a1, b, acc1);
        }
        #pragma unroll
        for (int r = 0; r < 4; ++r) {
            sC[kh][quad * 4 + r][ct * 16 + colb] = acc0[r];
            sC[kh][16 + quad * 4 + r][ct * 16 + colb] = acc1[r];
        }
    }
    __syncthreads();

    // ---- LN2 (tid < 512): sum partials, +b2 +zreg, layernorm -> out ----
    if (tid < 512) {
        const int row = tid >> 4, cg = tid & 15;
        float v[8];
        {
            f32x4 sA0 = *(const f32x4*)&sC[0][row][cg * 8];
            f32x4 sA1 = *(const f32x4*)&sC[0][row][cg * 8 + 4];
            f32x4 sB0 = *(const f32x4*)&sC[1][row][cg * 8];
            f32x4 sB1 = *(const f32x4*)&sC[1][row][cg * 8 + 4];
            float4 b0 = *(const float4*)&b2[cg * 8];
            float4 b1v = *(const float4*)&b2[cg * 8 + 4];
            v[0] = (sA0[0]+sB0[0])+b0.x+zreg[0]; v[1] = (sA0[1]+sB0[1])+b0.y+zreg[1];
            v[2] = (sA0[2]+sB0[2])+b0.z+zreg[2]; v[3] = (sA0[3]+sB0[3])+b0.w+zreg[3];
            v[4] = (sA1[0]+sB1[0])+b1v.x+zreg[4]; v[5] = (sA1[1]+sB1[1])+b1v.y+zreg[5];
            v[6] = (sA1[2]+sB1[2])+b1v.z+zreg[6]; v[7] = (sA1[3]+sB1[3])+b1v.w+zreg[7];
        }
        float s = v[0]+v[1]+v[2]+v[3]+v[4]+v[5]+v[6]+v[7];
        s += __shfl_xor(s, 1); s += __shfl_xor(s, 2);
        s += __shfl_xor(s, 4); s += __shfl_xor(s, 8);
        float mean = s * (1.0f / 128.0f);
        float d, vs = 0.f;
        #pragma unroll
        for (int j = 0; j < 8; ++j) { d = v[j] - mean; vs += d * d; }
        vs += __shfl_xor(vs, 1); vs += __shfl_xor(vs, 2);
        vs += __shfl_xor(vs, 4); vs += __shfl_xor(vs, 8);
        float rstd = rsqrtf(vs * (1.0f / 128.0f) + 1e-5f);
        float4 gg0 = *(const float4*)&g2[cg * 8], gg1 = *(const float4*)&g2[cg * 8 + 4];
        float4 bb0 = *(const float4*)&be2[cg * 8], bb1 = *(const float4*)&be2[cg * 8 + 4];
        size_t ob = (size_t)(t0 + row) * 128 + cg * 8;
        *(float4*)&out[ob] = make_float4(
            (v[0]-mean)*rstd*gg0.x+bb0.x, (v[1]-mean)*rstd*gg0.y+bb0.y,
            (v[2]-mean)*rstd*gg0.z+bb0.z, (v[3]-mean)*rstd*gg0.w+bb0.w);
        *(float4*)&out[ob + 4] = make_float4(
            (v[4]-mean)*rstd*gg1.x+bb1.x, (v[5]-mean)*rstd*gg1.y+bb1.y,
            (v[6]-mean)*rstd*gg1.z+bb1.z, (v[7]-mean)*rstd*gg1.w+bb1.w);
    }
}

// ---------------------------------------------------------------------------
extern "C" void kernel_launch(void* const* d_in, const int* in_sizes, int n_in,
                              void* d_out, int out_size, void* d_ws, size_t ws_size,
                              hipStream_t stream)
{
    (void)in_sizes; (void)n_in; (void)out_size; (void)ws_size;
    const float* x   = (const float*)d_in[0];
    const float* wq  = (const float*)d_in[1];
    const float* bq  = (const float*)d_in[2];
    const float* wk  = (const float*)d_in[3];
    const float* bk  = (const float*)d_in[4];
    const float* wv  = (const float*)d_in[5];
    const float* bv  = (const float*)d_in[6];
    const float* wo  = (const float*)d_in[7];
    const float* bo  = (const float*)d_in[8];
    const float* g1  = (const float*)d_in[9];
    const float* be1 = (const float*)d_in[10];
    const float* w1  = (const float*)d_in[11];
    const float* b1  = (const float*)d_in[12];
    const float* w2  = (const float*)d_in[13];
    const float* b2  = (const float*)d_in[14];
    const float* g2  = (const float*)d_in[15];
    const float* be2 = (const float*)d_in[16];

    char* ws = (char*)d_ws;
    const size_t MB = (size_t)1 << 20;
    u8*    Qblk = (u8*)(ws + 0 * MB);
    u8*    Kblk = (u8*)(ws + 16 * MB);
    u8*    Vblk = (u8*)(ws + 32 * MB);
    u16*   Zblk = (u16*)(ws + 48 * MB);
    // pre-attention scratch in Zblk region (dead after k_qkv):
    u16*   Xb  = (u16*)(ws + 48 * MB);
    u16*   Wqb = (u16*)(ws + 50 * MB);
    u16*   Wkb = (u16*)(ws + 50 * MB + 262144);
    u16*   Wvb = (u16*)(ws + 50 * MB + 524288);
    // tail weights + Vcol (own region, no aliasing):
    u16*   Wob  = (u16*)(ws + 64 * MB);
    u16*   W1b  = (u16*)(ws + 64 * MB + 524288);
    u16*   W2b  = (u16*)(ws + 64 * MB + 786432);
    float* Vcol = (float*)(ws + 65 * MB);
    float* out = (float*)d_out;

    k_prep<<<1440, 256, 0, stream>>>(x, wq, wk, wv, Xb, Wqb, Wkb, Wvb, Vcol);
    k_qkv<<<dim3(64, 18), 256, 0, stream>>>(Xb, Wqb, Wkb, Wvb, bq, bk, bv,
                                            wo, w1, w2,
                                            Qblk, Kblk, Vblk, Vcol,
                                            Wob, W1b, W2b);
    k_attn<<<4096, 256, 0, stream>>>(Qblk, Kblk, Vblk, Vcol, Zblk);
    k_tail<<<256, 1024, 0, stream>>>(Zblk, Wob, bo, x, g1, be1, W1b, b1, W2b, b2, g2, be2, out);
}